// Round 15
// baseline (206.291 us; speedup 1.0000x reference)
//
#include <hip/hip_runtime.h>
#include <hip/hip_bf16.h>

#define NN   100000
#define C0   40000
#define C1   30000
#define C2   30000
#define HID  64
#define KK   8
#define EE   1600000
#define DIN  512
#define NCLS 16
#define NB   196      // coarse dst buckets == node chunks (512 each)
#define BKE  2048     // edges per block in count pass
#define GR1  782      // ceil(EE/BKE)
#define BKS  1024     // edges per block in scatter pass (more TLP)
#define GRS  1563     // ceil(EE/BKS)
#define PMB  625      // pre_mfma blocks = C0/64
#define NBC  1568     // KK*NB node-bucket counts
#define SCH  7        // ceil(NBC/256) scan chunks
#define MAXT 1571     // upper bound on op-GEMM tiles
#define FCT  469      // ceil(30000/64) fc tiles per segment
#define GNT  1563     // ceil(100000/64) gnn tiles
#define AP   88       // LDS row pitch (bf16 units)

typedef unsigned short ushortT;
typedef __attribute__((ext_vector_type(8))) short bf16x8;
typedef __attribute__((ext_vector_type(4))) float f32x4;

__device__ __forceinline__ float b2f(ushortT u) {
    return __uint_as_float((unsigned)u << 16);
}
__device__ __forceinline__ ushortT f2b(float x) {
    unsigned v = __float_as_uint(x);
    unsigned r = (v + 0x7FFF + ((v >> 16) & 1)) >> 16;   // RNE
    return (ushortT)r;
}
__device__ __forceinline__ unsigned pk2(float lo, float hi) {
    return (unsigned)f2b(lo) | ((unsigned)f2b(hi) << 16);
}
__device__ __forceinline__ void acc8f(float* a, uint4 v) {
    a[0] += b2f((ushortT)(v.x & 0xFFFF)); a[1] += b2f((ushortT)(v.x >> 16));
    a[2] += b2f((ushortT)(v.y & 0xFFFF)); a[3] += b2f((ushortT)(v.y >> 16));
    a[4] += b2f((ushortT)(v.z & 0xFFFF)); a[5] += b2f((ushortT)(v.z >> 16));
    a[6] += b2f((ushortT)(v.w & 0xFFFF)); a[7] += b2f((ushortT)(v.w >> 16));
}

// ================ K0: WT conversion + bcnt zeroing ================
__global__ __launch_bounds__(256) void zero_wt(const float* __restrict__ W,
                                               ushortT* __restrict__ WT,
                                               int* __restrict__ bcnt) {
    const int t = threadIdx.x, b = blockIdx.x;
    if (b < 16) {
        int idx = b * 256 + t;   // 0..4095
        int c = idx >> 6, k8 = (idx & 63) * 8;
        uint4 v;
        v.x = pk2(W[(size_t)(k8 + 0) * HID + c], W[(size_t)(k8 + 1) * HID + c]);
        v.y = pk2(W[(size_t)(k8 + 2) * HID + c], W[(size_t)(k8 + 3) * HID + c]);
        v.z = pk2(W[(size_t)(k8 + 4) * HID + c], W[(size_t)(k8 + 5) * HID + c]);
        v.w = pk2(W[(size_t)(k8 + 6) * HID + c], W[(size_t)(k8 + 7) * HID + c]);
        *(uint4*)(WT + (size_t)c * DIN + k8) = v;
    } else {
        if (t < NB) bcnt[t] = 0;
    }
}

// ================ K1 fused: pre_mfma ∥ edge bucket counts ∥ node k-counts ================
__global__ __launch_bounds__(256) void fused_a(const float* __restrict__ A,
                                               const ushortT* __restrict__ WT,
                                               const float* __restrict__ bias,
                                               const int* __restrict__ dst,
                                               const int* __restrict__ na,
                                               int* __restrict__ bcnt,
                                               int* __restrict__ nbc,
                                               ushortT* __restrict__ hb) {
    __shared__ ushortT Ak[2][64 * AP];
    __shared__ ushortT Bk[2][64 * AP];
    const int tid = threadIdx.x, b = blockIdx.x;
    if (b < PMB) {
        const int row0 = b * 64;
        const int rr = tid >> 2, q = tid & 3;
        const int w = tid >> 6, l = tid & 63;
        const int lr = l & 15, g = l >> 4;
        f32x4 acc[4] = {{0.f,0.f,0.f,0.f},{0.f,0.f,0.f,0.f},{0.f,0.f,0.f,0.f},{0.f,0.f,0.f,0.f}};
        float4 av0, av1, av2, av3;
        uint4 bv0, bv1;
        {
            const float* ap = A + (size_t)(row0 + rr) * DIN + q * 16;
            av0 = *(const float4*)(ap + 0);  av1 = *(const float4*)(ap + 4);
            av2 = *(const float4*)(ap + 8);  av3 = *(const float4*)(ap + 12);
            const uint4* bp = (const uint4*)(WT + (size_t)rr * DIN + q * 16);
            bv0 = bp[0]; bv1 = bp[1];
        }
        {
            uint4 ua0, ua1;
            ua0.x = pk2(av0.x, av0.y); ua0.y = pk2(av0.z, av0.w);
            ua0.z = pk2(av1.x, av1.y); ua0.w = pk2(av1.z, av1.w);
            ua1.x = pk2(av2.x, av2.y); ua1.y = pk2(av2.z, av2.w);
            ua1.z = pk2(av3.x, av3.y); ua1.w = pk2(av3.z, av3.w);
            *(uint4*)&Ak[0][rr * AP + q * 16] = ua0;
            *(uint4*)&Ak[0][rr * AP + q * 16 + 8] = ua1;
            *(uint4*)&Bk[0][rr * AP + q * 16] = bv0;
            *(uint4*)&Bk[0][rr * AP + q * 16 + 8] = bv1;
        }
        __syncthreads();
        for (int tt = 0; tt < 8; ++tt) {
            if (tt < 7) {
                const int k0 = (tt + 1) * 64;
                const float* ap = A + (size_t)(row0 + rr) * DIN + k0 + q * 16;
                av0 = *(const float4*)(ap + 0);  av1 = *(const float4*)(ap + 4);
                av2 = *(const float4*)(ap + 8);  av3 = *(const float4*)(ap + 12);
                const uint4* bp = (const uint4*)(WT + (size_t)rr * DIN + k0 + q * 16);
                bv0 = bp[0]; bv1 = bp[1];
            }
            const int bu = tt & 1;
            #pragma unroll
            for (int s = 0; s < 2; ++s) {
                bf16x8 af = *(const bf16x8*)&Ak[bu][(w * 16 + lr) * AP + s * 32 + g * 8];
                #pragma unroll
                for (int n = 0; n < 4; ++n) {
                    bf16x8 bf = *(const bf16x8*)&Bk[bu][(n * 16 + lr) * AP + s * 32 + g * 8];
                    acc[n] = __builtin_amdgcn_mfma_f32_16x16x32_bf16(af, bf, acc[n], 0, 0, 0);
                }
            }
            if (tt < 7) {
                const int nb2 = (tt + 1) & 1;
                uint4 ua0, ua1;
                ua0.x = pk2(av0.x, av0.y); ua0.y = pk2(av0.z, av0.w);
                ua0.z = pk2(av1.x, av1.y); ua0.w = pk2(av1.z, av1.w);
                ua1.x = pk2(av2.x, av2.y); ua1.y = pk2(av2.z, av2.w);
                ua1.z = pk2(av3.x, av3.y); ua1.w = pk2(av3.z, av3.w);
                *(uint4*)&Ak[nb2][rr * AP + q * 16] = ua0;
                *(uint4*)&Ak[nb2][rr * AP + q * 16 + 8] = ua1;
                *(uint4*)&Bk[nb2][rr * AP + q * 16] = bv0;
                *(uint4*)&Bk[nb2][rr * AP + q * 16 + 8] = bv1;
            }
            __syncthreads();
        }
        #pragma unroll
        for (int n = 0; n < 4; ++n) {
            float bb = bias[n * 16 + lr];
            #pragma unroll
            for (int i = 0; i < 4; ++i) {
                int row = row0 + w * 16 + g * 4 + i;
                hb[(size_t)row * HID + n * 16 + lr] = f2b(acc[n][i] + bb);
            }
        }
    } else if (b < PMB + GR1) {
        int* sh = (int*)&Ak[0][0];
        for (int i = tid; i < NB; i += 256) sh[i] = 0;
        __syncthreads();
        const int base = (b - PMB) * BKE;
        for (int u = 0; u < BKE / 256; ++u) {
            int e = base + tid + u * 256;
            if (e < EE) atomicAdd(&sh[dst[e] >> 9], 1);
        }
        __syncthreads();
        for (int i = tid; i < NB; i += 256) {
            int c = sh[i];
            if (c) atomicAdd(&bcnt[i], c);
        }
    } else {
        int* sh = (int*)&Ak[0][0];
        const int nb_ = b - PMB - GR1;
        if (tid < KK) sh[tid] = 0;
        __syncthreads();
        #pragma unroll
        for (int u = 0; u < 2; ++u) {
            int n = nb_ * 512 + tid + u * 256;
            if (n < NN) atomicAdd(&sh[na[n]], 1);
        }
        __syncthreads();
        if (tid < KK) nbc[tid * NB + nb_] = sh[tid];
    }
}

// ================ K3: bucket_scan (parallel) + nb_scan (merged) ================
__global__ __launch_bounds__(256) void scan_k(const int* __restrict__ bcnt,
                                              int* __restrict__ bbase,
                                              int* __restrict__ bcur,
                                              int* __restrict__ offs,
                                              const int* __restrict__ nbc,
                                              int* __restrict__ gbase,
                                              int* __restrict__ koff,
                                              int* __restrict__ tmap_b,
                                              int* __restrict__ tmap_s) {
    __shared__ int sm[256];
    const int t = threadIdx.x;
    if (blockIdx.x == 0) {
        int v = (t < NB) ? bcnt[t] : 0;
        sm[t] = v;
        __syncthreads();
        for (int off = 1; off < 256; off <<= 1) {
            int y = (t >= off) ? sm[t - off] : 0;
            __syncthreads();
            sm[t] += y;
            __syncthreads();
        }
        if (t < NB) {
            int excl = sm[t] - v;
            bbase[t] = excl;
            bcur[t] = excl;
        }
        if (t == 0) offs[NN] = EE;
        return;
    }
    __shared__ int carry;
    __shared__ int tl[KK];
    if (t == 0) carry = 0;
    for (int i = t; i < MAXT; i += 256) tmap_b[i] = -1;
    __syncthreads();
    for (int c = 0; c < SCH; ++c) {
        int i = c * 256 + t;
        int v = (i < NBC) ? nbc[i] : 0;
        sm[t] = v;
        __syncthreads();
        for (int off = 1; off < 256; off <<= 1) {
            int y = (t >= off) ? sm[t - off] : 0;
            __syncthreads();
            sm[t] += y;
            __syncthreads();
        }
        int base = carry;
        int excl = base + sm[t] - v;
        if (i < NBC) {
            gbase[i] = excl;
            if ((i % NB) == 0) koff[i / NB] = excl;
        }
        __syncthreads();
        if (t == 255) carry = base + sm[255];
        __syncthreads();
    }
    if (t == 0) {
        koff[KK] = NN;
        int run = 0;
        for (int k = 0; k < KK; ++k) {
            tl[k] = run;
            int cnt = ((k == KK - 1) ? NN : koff[k + 1]) - koff[k];
            run += (cnt + 63) / 64;
        }
    }
    __syncthreads();
    if (t < KK) {
        int k = t;
        int kb = koff[k];
        int ke = (k == KK - 1) ? NN : koff[k + 1];
        int nt = (ke - kb + 63) / 64;
        for (int tt = 0; tt < nt; ++tt) {
            tmap_b[tl[k] + tt] = k;
            tmap_s[tl[k] + tt] = kb + tt * 64;
        }
    }
}

// ================ K4: coarse_scatter (BKS=1024, more TLP) + nb_scatter ================
__global__ __launch_bounds__(256) void scatter_k(const int* __restrict__ src,
                                                 const int* __restrict__ dst,
                                                 int* __restrict__ bcur,
                                                 unsigned* __restrict__ ebuf,
                                                 const int* __restrict__ na,
                                                 const int* __restrict__ gbase,
                                                 int* __restrict__ perm) {
    __shared__ int s1[NB];
    __shared__ int s2[NB];
    const int t = threadIdx.x, b = blockIdx.x;
    if (b < GRS) {
        for (int i = t; i < NB; i += 256) s1[i] = 0;
        __syncthreads();
        const int base = b * BKS;
        unsigned mypk[4]; int mybin[4], myrank[4];
        #pragma unroll
        for (int u = 0; u < 4; ++u) {
            int e = base + t + u * 256;
            if (e < EE) {
                int d = dst[e];
                int s = src[e];
                mybin[u] = d >> 9;
                mypk[u] = (unsigned)s |
                          ((unsigned)(((d & 511) << 1) | (s < C0 ? 0 : 1)) << 17);
                myrank[u] = atomicAdd(&s1[mybin[u]], 1);
            } else mybin[u] = -1;
        }
        __syncthreads();
        for (int i = t; i < NB; i += 256) {
            int c = s1[i];
            s2[i] = c ? atomicAdd(&bcur[i], c) : 0;
        }
        __syncthreads();
        #pragma unroll
        for (int u = 0; u < 4; ++u) {
            if (mybin[u] >= 0) {
                ebuf[s2[mybin[u]] + myrank[u]] = mypk[u];
            }
        }
    } else {
        const int nb_ = b - GRS;
        if (t < KK) { s1[t] = 0; s2[t] = gbase[t * NB + nb_]; }
        __syncthreads();
        #pragma unroll
        for (int u = 0; u < 2; ++u) {
            int n = nb_ * 512 + t + u * 256;
            if (n < NN) {
                int k = na[n];
                int r = atomicAdd(&s1[k], 1);
                perm[s2[k] + r] = n;
            }
        }
    }
}

// ================ r2: per-bucket exact CSR (1024 threads/block) ================
__global__ __launch_bounds__(1024) void fine_scatter(const unsigned* __restrict__ ebuf,
                                                     const int* __restrict__ bbase,
                                                     const int* __restrict__ bend,
                                                     int* __restrict__ offs,
                                                     int* __restrict__ split,
                                                     int* __restrict__ ssrc) {
    __shared__ int hist[1024];
    __shared__ int lofs[1024];
    __shared__ int sm[1024];
    const int t = threadIdx.x, b = blockIdx.x;
    const int beg = bbase[b], end = bend[b];
    hist[t] = 0;
    __syncthreads();
    for (int j = beg + t; j < end; j += 1024) {
        atomicAdd(&hist[ebuf[j] >> 17], 1);
    }
    __syncthreads();
    int v = hist[t];
    sm[t] = v;
    __syncthreads();
    for (int off = 1; off < 1024; off <<= 1) {
        int y = (t >= off) ? sm[t - off] : 0;
        __syncthreads();
        sm[t] += y;
        __syncthreads();
    }
    lofs[t] = sm[t] - v;   // exclusive prefix
    __syncthreads();
    if (t < 512) {
        int n = b * 512 + t;
        if (n < NN) {
            offs[n]  = beg + lofs[2 * t];
            split[n] = beg + lofs[2 * t + 1];
        }
    }
    __syncthreads();
    for (int j = beg + t; j < end; j += 1024) {
        unsigned pk = ebuf[j];
        int pos = beg + atomicAdd(&lofs[pk >> 17], 1);
        ssrc[pos] = (int)(pk & 0x1FFFFu);
    }
}

// ================ spmm v3: 8 lanes/node (16B each), 32 nodes/block, 8-deep ILP ================
__global__ __launch_bounds__(256) void spmm(const ushortT* __restrict__ rows,
                                            const int* __restrict__ offs,
                                            const int* __restrict__ splt,
                                            const int* __restrict__ ssrc,
                                            ushortT* __restrict__ aggb) {
    const int t = threadIdx.x;
    const int g = t >> 3, c8 = t & 7;
    const int n = blockIdx.x * 32 + g;
    const int beg = offs[n], endf = offs[n + 1];
    const int ge = splt ? splt[n] : endf;
    float a[8] = {}, c[8] = {};
    int j = beg;
    for (; j + 8 <= ge; j += 8) {
        int s0 = ssrc[j + 0], s1 = ssrc[j + 1], s2 = ssrc[j + 2], s3 = ssrc[j + 3];
        int s4 = ssrc[j + 4], s5 = ssrc[j + 5], s6 = ssrc[j + 6], s7 = ssrc[j + 7];
        uint4 v0 = *(const uint4*)(rows + (size_t)s0 * HID + c8 * 8);
        uint4 v1 = *(const uint4*)(rows + (size_t)s1 * HID + c8 * 8);
        uint4 v2 = *(const uint4*)(rows + (size_t)s2 * HID + c8 * 8);
        uint4 v3 = *(const uint4*)(rows + (size_t)s3 * HID + c8 * 8);
        uint4 v4 = *(const uint4*)(rows + (size_t)s4 * HID + c8 * 8);
        uint4 v5 = *(const uint4*)(rows + (size_t)s5 * HID + c8 * 8);
        uint4 v6 = *(const uint4*)(rows + (size_t)s6 * HID + c8 * 8);
        uint4 v7 = *(const uint4*)(rows + (size_t)s7 * HID + c8 * 8);
        acc8f(a, v0); acc8f(c, v1); acc8f(a, v2); acc8f(c, v3);
        acc8f(a, v4); acc8f(c, v5); acc8f(a, v6); acc8f(c, v7);
    }
    if (j + 4 <= ge) {
        int s0 = ssrc[j + 0], s1 = ssrc[j + 1], s2 = ssrc[j + 2], s3 = ssrc[j + 3];
        uint4 v0 = *(const uint4*)(rows + (size_t)s0 * HID + c8 * 8);
        uint4 v1 = *(const uint4*)(rows + (size_t)s1 * HID + c8 * 8);
        uint4 v2 = *(const uint4*)(rows + (size_t)s2 * HID + c8 * 8);
        uint4 v3 = *(const uint4*)(rows + (size_t)s3 * HID + c8 * 8);
        acc8f(a, v0); acc8f(c, v1); acc8f(a, v2); acc8f(c, v3);
        j += 4;
    }
    for (; j < ge; ++j) {
        uint4 v = *(const uint4*)(rows + (size_t)ssrc[j] * HID + c8 * 8);
        acc8f(a, v);
    }
    const float inv = 1.0f / fmaxf((float)(endf - beg), 1.0f);
    #pragma unroll
    for (int i = 0; i < 8; ++i) a[i] = (a[i] + c[i]) * inv;
    uint4 o;
    o.x = pk2(a[0], a[1]); o.y = pk2(a[2], a[3]);
    o.z = pk2(a[4], a[5]); o.w = pk2(a[6], a[7]);
    *(uint4*)(aggb + (size_t)n * HID + c8 * 8) = o;
}

// ================ op GEMM via MFMA: k-bucketed tiles, bf16 agg -> htb ================
__global__ __launch_bounds__(256) void op_gemm(const ushortT* __restrict__ aggb,
                                               const ushortT* __restrict__ hb,
                                               const int* __restrict__ perm,
                                               const int* __restrict__ koff,
                                               const int* __restrict__ tmap_b,
                                               const int* __restrict__ tmap_s,
                                               const float* __restrict__ op_W,
                                               const float* __restrict__ op_b,
                                               const float* __restrict__ emb_W,
                                               const float* __restrict__ emb_b,
                                               ushortT* __restrict__ htb) {
    __shared__ ushortT Ak[64 * AP];
    __shared__ ushortT Bk[64 * AP];
    __shared__ int idx[64];
    const int bk = tmap_b[blockIdx.x];
    if (bk < 0) return;
    const int start = tmap_s[blockIdx.x];
    const int kend = koff[bk + 1];
    const int tid = threadIdx.x;
    const int rr = tid >> 2, q = tid & 3;
    if (tid < 64) {
        int p = start + tid;
        idx[tid] = (p < kend) ? perm[p] : -1;
    }
    __syncthreads();
    {
        int n = idx[rr];
        uint4 a0 = {0,0,0,0}, a1 = {0,0,0,0};
        if (n >= 0) {
            const uint4* p = (const uint4*)(aggb + (size_t)n * HID + q * 16);
            a0 = p[0]; a1 = p[1];
        }
        *(uint4*)&Ak[rr * AP + q * 16] = a0;
        *(uint4*)&Ak[rr * AP + q * 16 + 8] = a1;
    }
    {
        const float* wp = op_W + (size_t)bk * HID * HID;
        #pragma unroll
        for (int j = 0; j < 16; ++j) {
            Bk[rr * AP + q * 16 + j] = f2b(wp[(size_t)(q * 16 + j) * HID + rr]);
        }
    }
    __syncthreads();
    const int w = tid >> 6, l = tid & 63;
    const int lr = l & 15, g = l >> 4;
    f32x4 acc[4] = {{0.f,0.f,0.f,0.f},{0.f,0.f,0.f,0.f},{0.f,0.f,0.f,0.f},{0.f,0.f,0.f,0.f}};
    #pragma unroll
    for (int s = 0; s < 2; ++s) {
        bf16x8 af = *(const bf16x8*)&Ak[(w * 16 + lr) * AP + s * 32 + g * 8];
        #pragma unroll
        for (int n = 0; n < 4; ++n) {
            bf16x8 bf = *(const bf16x8*)&Bk[(n * 16 + lr) * AP + s * 32 + g * 8];
            acc[n] = __builtin_amdgcn_mfma_f32_16x16x32_bf16(af, bf, acc[n], 0, 0, 0);
        }
    }
    #pragma unroll
    for (int n = 0; n < 4; ++n) {
        const int col = n * 16 + lr;
        float ob = op_b[bk * HID + col];
        #pragma unroll
        for (int i = 0; i < 4; ++i) {
            int node = idx[w * 16 + g * 4 + i];
            if (node < 0) continue;
            float v = acc[n][i] + ob;
            if (node < C0) {
                v += b2f(hb[(size_t)node * HID + col]);
            } else {
                int si = (node < C0 + C1) ? 0 : 1;
                int rn = node - C0 - si * C1;
                v += emb_W[((size_t)si * C1 + rn) * HID + col] + emb_b[si * HID + col];
            }
            htb[(size_t)node * HID + col] = f2b(v);
        }
    }
}

// ================ fc GEMM via MFMA: contiguous segment rows, in-place htb ================
__global__ __launch_bounds__(256) void fc_gemm(ushortT* __restrict__ htb,
                                               const float* __restrict__ fc_W,
                                               const float* __restrict__ fc_b) {
    __shared__ ushortT Ak[64 * AP];
    __shared__ ushortT Bk[64 * AP];
    const int si = (blockIdx.x < FCT) ? 0 : 1;
    const int t0 = blockIdx.x - si * FCT;
    const int row0 = C0 + si * C1 + t0 * 64;
    const int lim = C0 + (si + 1) * C1;
    const int tid = threadIdx.x;
    const int rr = tid >> 2, q = tid & 3;
    {
        int n = row0 + rr;
        uint4 a0 = {0,0,0,0}, a1 = {0,0,0,0};
        if (n < lim) {
            const uint4* p = (const uint4*)(htb + (size_t)n * HID + q * 16);
            a0 = p[0]; a1 = p[1];
        }
        *(uint4*)&Ak[rr * AP + q * 16] = a0;
        *(uint4*)&Ak[rr * AP + q * 16 + 8] = a1;
    }
    {
        const float* wp = fc_W + (size_t)si * HID * HID;
        #pragma unroll
        for (int j = 0; j < 16; ++j) {
            Bk[rr * AP + q * 16 + j] = f2b(wp[(size_t)(q * 16 + j) * HID + rr]);
        }
    }
    __syncthreads();
    const int w = tid >> 6, l = tid & 63;
    const int lr = l & 15, g = l >> 4;
    f32x4 acc[4] = {{0.f,0.f,0.f,0.f},{0.f,0.f,0.f,0.f},{0.f,0.f,0.f,0.f},{0.f,0.f,0.f,0.f}};
    #pragma unroll
    for (int s = 0; s < 2; ++s) {
        bf16x8 af = *(const bf16x8*)&Ak[(w * 16 + lr) * AP + s * 32 + g * 8];
        #pragma unroll
        for (int n = 0; n < 4; ++n) {
            bf16x8 bf = *(const bf16x8*)&Bk[(n * 16 + lr) * AP + s * 32 + g * 8];
            acc[n] = __builtin_amdgcn_mfma_f32_16x16x32_bf16(af, bf, acc[n], 0, 0, 0);
        }
    }
    #pragma unroll
    for (int n = 0; n < 4; ++n) {
        const int col = n * 16 + lr;
        float fb = fc_b[si * HID + col];
        #pragma unroll
        for (int i = 0; i < 4; ++i) {
            int node = row0 + w * 16 + g * 4 + i;
            if (node >= lim) continue;
            htb[(size_t)node * HID + col] = f2b(acc[n][i] + fb);
        }
    }
}

// ================ gnn GEMM via MFMA + elu + logits (reads bf16 agg) ================
__global__ __launch_bounds__(256) void gnn_logits(const ushortT* __restrict__ aggb,
                                                  const float* __restrict__ gnn_W,
                                                  const float* __restrict__ gnn_b,
                                                  const float* __restrict__ out_W,
                                                  const float* __restrict__ out_b,
                                                  float* __restrict__ out) {
    __shared__ ushortT Ak[64 * AP];
    __shared__ ushortT Bk[64 * AP];
    __shared__ float Em[64][65];
    __shared__ float Wo[64 * NCLS];
    const int row0 = blockIdx.x * 64;
    const int tid = threadIdx.x;
    const int rr = tid >> 2, q = tid & 3;
    {
        int n = row0 + rr;
        uint4 a0 = {0,0,0,0}, a1 = {0,0,0,0};
        if (n < NN) {
            const uint4* p = (const uint4*)(aggb + (size_t)n * HID + q * 16);
            a0 = p[0]; a1 = p[1];
        }
        *(uint4*)&Ak[rr * AP + q * 16] = a0;
        *(uint4*)&Ak[rr * AP + q * 16 + 8] = a1;
    }
    {
        #pragma unroll
        for (int j = 0; j < 16; ++j) {
            Bk[rr * AP + q * 16 + j] = f2b(gnn_W[(size_t)(q * 16 + j) * HID + rr]);
        }
    }
    *(float4*)(&Wo[tid * 4]) = *(const float4*)(out_W + tid * 4);
    __syncthreads();
    const int w = tid >> 6, l = tid & 63;
    const int lr = l & 15, g = l >> 4;
    f32x4 acc[4] = {{0.f,0.f,0.f,0.f},{0.f,0.f,0.f,0.f},{0.f,0.f,0.f,0.f},{0.f,0.f,0.f,0.f}};
    #pragma unroll
    for (int s = 0; s < 2; ++s) {
        bf16x8 af = *(const bf16x8*)&Ak[(w * 16 + lr) * AP + s * 32 + g * 8];
        #pragma unroll
        for (int n = 0; n < 4; ++n) {
            bf16x8 bf = *(const bf16x8*)&Bk[(n * 16 + lr) * AP + s * 32 + g * 8];
            acc[n] = __builtin_amdgcn_mfma_f32_16x16x32_bf16(af, bf, acc[n], 0, 0, 0);
        }
    }
    #pragma unroll
    for (int n = 0; n < 4; ++n) {
        const int col = n * 16 + lr;
        float gb = gnn_b[col];
        #pragma unroll
        for (int i = 0; i < 4; ++i) {
            int lrow = w * 16 + g * 4 + i;
            int node = row0 + lrow;
            float v = acc[n][i] + gb;
            v = (v > 0.f) ? v : expm1f(v);
            Em[lrow][col] = v;
            if (node < NN) out[(size_t)node * HID + col] = v;
        }
    }
    __syncthreads();
    const int r = tid >> 2, cq = (tid & 3) * 4;
    float l0 = 0.f, l1 = 0.f, l2 = 0.f, l3 = 0.f;
    #pragma unroll 8
    for (int j = 0; j < 64; ++j) {
        float e = Em[r][j];
        float4 wv = *(const float4*)(&Wo[j * NCLS + cq]);
        l0 += e * wv.x; l1 += e * wv.y; l2 += e * wv.z; l3 += e * wv.w;
    }
    int n = row0 + r;
    if (n < NN) {
        float4 ob = *(const float4*)(out_b + cq);
        float4 lg;
        lg.x = l0 + ob.x; lg.y = l1 + ob.y; lg.z = l2 + ob.z; lg.w = l3 + ob.w;
        const size_t lbase = (size_t)NN * HID;
        *(float4*)(out + lbase + (size_t)n * NCLS + cq) = lg;
        *(float4*)(out + lbase + (size_t)NN * NCLS + (size_t)n * NCLS + cq) = lg;
    }
}

extern "C" void kernel_launch(void* const* d_in, const int* in_sizes, int n_in,
                              void* d_out, int out_size, void* d_ws, size_t ws_size,
                              hipStream_t stream) {
    const float* feats0 = (const float*)d_in[0];
    const float* W_pre  = (const float*)d_in[1];
    const float* b_pre  = (const float*)d_in[2];
    const float* emb_W  = (const float*)d_in[3];
    const float* emb_b  = (const float*)d_in[4];
    const float* op_W   = (const float*)d_in[5];
    const float* op_b   = (const float*)d_in[6];
    const float* fc_W   = (const float*)d_in[7];
    const float* fc_b   = (const float*)d_in[8];
    const float* gnn_W  = (const float*)d_in[9];
    const float* gnn_b  = (const float*)d_in[10];
    const float* out_W  = (const float*)d_in[11];
    const float* out_b  = (const float*)d_in[12];
    const int* src         = (const int*)d_in[13];
    const int* dst         = (const int*)d_in[14];
    const int* node_assign = (const int*)d_in[15];
    float* out = (float*)d_out;

    // workspace layout (~38 MB). aggb (12.8MB) aliases ebuf (6.4MB packed).
    ushortT* hb  = (ushortT*)d_ws;                     // C0*HID bf16
    ushortT* htb = hb + (size_t)C0 * HID;              // NN*HID bf16
    ushortT* aggb = htb + (size_t)NN * HID;            // NN*HID bf16 (union w/ ebuf)
    unsigned* ebuf = (unsigned*)aggb;                  // EE u32 (alias)
    ushortT* WT = aggb + (size_t)NN * HID;             // 64*512 bf16
    int* ssrc   = (int*)(WT + (size_t)HID * DIN);      // EE
    int* offs   = ssrc + EE;                           // NN+1
    int* split  = offs + NN + 1;                       // NN
    int* perm   = split + NN;                          // NN
    int* nbc    = perm + NN;                           // NBC
    int* gbase  = nbc + NBC;                           // NBC
    int* koff   = gbase + NBC;                         // KK+1
    int* tmap_b = koff + KK + 1;                       // MAXT
    int* tmap_s = tmap_b + MAXT;                       // MAXT
    int* bcnt   = tmap_s + MAXT;                       // NB
    int* bbase  = bcnt + NB;                           // NB
    int* bcur   = bbase + NB;                          // NB

    zero_wt<<<17, 256, 0, stream>>>(W_pre, WT, bcnt);
    fused_a<<<PMB + GR1 + NB, 256, 0, stream>>>(feats0, WT, b_pre, dst, node_assign,
                                                bcnt, nbc, hb);
    scan_k<<<2, 256, 0, stream>>>(bcnt, bbase, bcur, offs, nbc, gbase, koff, tmap_b, tmap_s);
    scatter_k<<<GRS + NB, 256, 0, stream>>>(src, dst, bcur, ebuf, node_assign, gbase, perm);
    fine_scatter<<<NB, 1024, 0, stream>>>(ebuf, bbase, bcur, offs, split, ssrc);
    spmm<<<NN / 32, 256, 0, stream>>>(hb, offs, split, ssrc, aggb);          // filtered
    op_gemm<<<MAXT, 256, 0, stream>>>(aggb, hb, perm, koff, tmap_b, tmap_s,
                                      op_W, op_b, emb_W, emb_b, htb);
    fc_gemm<<<2 * FCT, 256, 0, stream>>>(htb, fc_W, fc_b);
    spmm<<<NN / 32, 256, 0, stream>>>(htb, offs, nullptr, ssrc, aggb);       // full
    gnn_logits<<<GNT, 256, 0, stream>>>(aggb, gnn_W, gnn_b, out_W, out_b, out);
}

// Round 16
// 187.622 us; speedup vs baseline: 1.0995x; 1.0995x over previous
//
#include <hip/hip_runtime.h>
#include <hip/hip_bf16.h>

#define NN   100000
#define C0   40000
#define C1   30000
#define C2   30000
#define HID  64
#define KK   8
#define EE   1600000
#define DIN  512
#define NCLS 16
#define NB   196      // coarse dst buckets == node chunks (512 each)
#define BKE  2048     // edges per block in count+scatter passes
#define GR1  782      // ceil(EE/BKE)
#define PMB  625      // pre_mfma blocks = C0/64
#define NBC  1568     // KK*NB node-bucket counts
#define SCH  7        // ceil(NBC/256) scan chunks
#define MAXT 1571     // upper bound on op-GEMM tiles
#define FCT  469      // ceil(30000/64) fc tiles per segment
#define GNT  1563     // ceil(100000/64) gnn tiles
#define AP   88       // LDS row pitch (bf16 units)

typedef unsigned short ushortT;
typedef __attribute__((ext_vector_type(8))) short bf16x8;
typedef __attribute__((ext_vector_type(4))) float f32x4;

__device__ __forceinline__ float b2f(ushortT u) {
    return __uint_as_float((unsigned)u << 16);
}
__device__ __forceinline__ ushortT f2b(float x) {
    unsigned v = __float_as_uint(x);
    unsigned r = (v + 0x7FFF + ((v >> 16) & 1)) >> 16;   // RNE
    return (ushortT)r;
}
__device__ __forceinline__ unsigned pk2(float lo, float hi) {
    return (unsigned)f2b(lo) | ((unsigned)f2b(hi) << 16);
}
__device__ __forceinline__ void acc8f(float* a, uint4 v) {
    a[0] += b2f((ushortT)(v.x & 0xFFFF)); a[1] += b2f((ushortT)(v.x >> 16));
    a[2] += b2f((ushortT)(v.y & 0xFFFF)); a[3] += b2f((ushortT)(v.y >> 16));
    a[4] += b2f((ushortT)(v.z & 0xFFFF)); a[5] += b2f((ushortT)(v.z >> 16));
    a[6] += b2f((ushortT)(v.w & 0xFFFF)); a[7] += b2f((ushortT)(v.w >> 16));
}

// ================ K0: WT conversion + bcnt zeroing ================
__global__ __launch_bounds__(256) void zero_wt(const float* __restrict__ W,
                                               ushortT* __restrict__ WT,
                                               int* __restrict__ bcnt) {
    const int t = threadIdx.x, b = blockIdx.x;
    if (b < 16) {
        int idx = b * 256 + t;   // 0..4095
        int c = idx >> 6, k8 = (idx & 63) * 8;
        uint4 v;
        v.x = pk2(W[(size_t)(k8 + 0) * HID + c], W[(size_t)(k8 + 1) * HID + c]);
        v.y = pk2(W[(size_t)(k8 + 2) * HID + c], W[(size_t)(k8 + 3) * HID + c]);
        v.z = pk2(W[(size_t)(k8 + 4) * HID + c], W[(size_t)(k8 + 5) * HID + c]);
        v.w = pk2(W[(size_t)(k8 + 6) * HID + c], W[(size_t)(k8 + 7) * HID + c]);
        *(uint4*)(WT + (size_t)c * DIN + k8) = v;
    } else {
        if (t < NB) bcnt[t] = 0;
    }
}

// ================ K1 fused: pre_mfma ∥ edge bucket counts ∥ node k-counts ================
__global__ __launch_bounds__(256) void fused_a(const float* __restrict__ A,
                                               const ushortT* __restrict__ WT,
                                               const float* __restrict__ bias,
                                               const int* __restrict__ dst,
                                               const int* __restrict__ na,
                                               int* __restrict__ bcnt,
                                               int* __restrict__ nbc,
                                               ushortT* __restrict__ hb) {
    __shared__ ushortT Ak[2][64 * AP];
    __shared__ ushortT Bk[2][64 * AP];
    const int tid = threadIdx.x, b = blockIdx.x;
    if (b < PMB) {
        const int row0 = b * 64;
        const int rr = tid >> 2, q = tid & 3;
        const int w = tid >> 6, l = tid & 63;
        const int lr = l & 15, g = l >> 4;
        f32x4 acc[4] = {{0.f,0.f,0.f,0.f},{0.f,0.f,0.f,0.f},{0.f,0.f,0.f,0.f},{0.f,0.f,0.f,0.f}};
        float4 av0, av1, av2, av3;
        uint4 bv0, bv1;
        {
            const float* ap = A + (size_t)(row0 + rr) * DIN + q * 16;
            av0 = *(const float4*)(ap + 0);  av1 = *(const float4*)(ap + 4);
            av2 = *(const float4*)(ap + 8);  av3 = *(const float4*)(ap + 12);
            const uint4* bp = (const uint4*)(WT + (size_t)rr * DIN + q * 16);
            bv0 = bp[0]; bv1 = bp[1];
        }
        {
            uint4 ua0, ua1;
            ua0.x = pk2(av0.x, av0.y); ua0.y = pk2(av0.z, av0.w);
            ua0.z = pk2(av1.x, av1.y); ua0.w = pk2(av1.z, av1.w);
            ua1.x = pk2(av2.x, av2.y); ua1.y = pk2(av2.z, av2.w);
            ua1.z = pk2(av3.x, av3.y); ua1.w = pk2(av3.z, av3.w);
            *(uint4*)&Ak[0][rr * AP + q * 16] = ua0;
            *(uint4*)&Ak[0][rr * AP + q * 16 + 8] = ua1;
            *(uint4*)&Bk[0][rr * AP + q * 16] = bv0;
            *(uint4*)&Bk[0][rr * AP + q * 16 + 8] = bv1;
        }
        __syncthreads();
        for (int tt = 0; tt < 8; ++tt) {
            if (tt < 7) {
                const int k0 = (tt + 1) * 64;
                const float* ap = A + (size_t)(row0 + rr) * DIN + k0 + q * 16;
                av0 = *(const float4*)(ap + 0);  av1 = *(const float4*)(ap + 4);
                av2 = *(const float4*)(ap + 8);  av3 = *(const float4*)(ap + 12);
                const uint4* bp = (const uint4*)(WT + (size_t)rr * DIN + k0 + q * 16);
                bv0 = bp[0]; bv1 = bp[1];
            }
            const int bu = tt & 1;
            #pragma unroll
            for (int s = 0; s < 2; ++s) {
                bf16x8 af = *(const bf16x8*)&Ak[bu][(w * 16 + lr) * AP + s * 32 + g * 8];
                #pragma unroll
                for (int n = 0; n < 4; ++n) {
                    bf16x8 bf = *(const bf16x8*)&Bk[bu][(n * 16 + lr) * AP + s * 32 + g * 8];
                    acc[n] = __builtin_amdgcn_mfma_f32_16x16x32_bf16(af, bf, acc[n], 0, 0, 0);
                }
            }
            if (tt < 7) {
                const int nb2 = (tt + 1) & 1;
                uint4 ua0, ua1;
                ua0.x = pk2(av0.x, av0.y); ua0.y = pk2(av0.z, av0.w);
                ua0.z = pk2(av1.x, av1.y); ua0.w = pk2(av1.z, av1.w);
                ua1.x = pk2(av2.x, av2.y); ua1.y = pk2(av2.z, av2.w);
                ua1.z = pk2(av3.x, av3.y); ua1.w = pk2(av3.z, av3.w);
                *(uint4*)&Ak[nb2][rr * AP + q * 16] = ua0;
                *(uint4*)&Ak[nb2][rr * AP + q * 16 + 8] = ua1;
                *(uint4*)&Bk[nb2][rr * AP + q * 16] = bv0;
                *(uint4*)&Bk[nb2][rr * AP + q * 16 + 8] = bv1;
            }
            __syncthreads();
        }
        #pragma unroll
        for (int n = 0; n < 4; ++n) {
            float bb = bias[n * 16 + lr];
            #pragma unroll
            for (int i = 0; i < 4; ++i) {
                int row = row0 + w * 16 + g * 4 + i;
                hb[(size_t)row * HID + n * 16 + lr] = f2b(acc[n][i] + bb);
            }
        }
    } else if (b < PMB + GR1) {
        int* sh = (int*)&Ak[0][0];
        for (int i = tid; i < NB; i += 256) sh[i] = 0;
        __syncthreads();
        const int base = (b - PMB) * BKE;
        for (int u = 0; u < BKE / 256; ++u) {
            int e = base + tid + u * 256;
            if (e < EE) atomicAdd(&sh[dst[e] >> 9], 1);
        }
        __syncthreads();
        for (int i = tid; i < NB; i += 256) {
            int c = sh[i];
            if (c) atomicAdd(&bcnt[i], c);
        }
    } else {
        int* sh = (int*)&Ak[0][0];
        const int nb_ = b - PMB - GR1;
        if (tid < KK) sh[tid] = 0;
        __syncthreads();
        #pragma unroll
        for (int u = 0; u < 2; ++u) {
            int n = nb_ * 512 + tid + u * 256;
            if (n < NN) atomicAdd(&sh[na[n]], 1);
        }
        __syncthreads();
        if (tid < KK) nbc[tid * NB + nb_] = sh[tid];
    }
}

// ================ K3: bucket_scan (parallel) + nb_scan (merged) ================
__global__ __launch_bounds__(256) void scan_k(const int* __restrict__ bcnt,
                                              int* __restrict__ bbase,
                                              int* __restrict__ bcur,
                                              int* __restrict__ offs,
                                              const int* __restrict__ nbc,
                                              int* __restrict__ gbase,
                                              int* __restrict__ koff,
                                              int* __restrict__ tmap_b,
                                              int* __restrict__ tmap_s) {
    __shared__ int sm[256];
    const int t = threadIdx.x;
    if (blockIdx.x == 0) {
        int v = (t < NB) ? bcnt[t] : 0;
        sm[t] = v;
        __syncthreads();
        for (int off = 1; off < 256; off <<= 1) {
            int y = (t >= off) ? sm[t - off] : 0;
            __syncthreads();
            sm[t] += y;
            __syncthreads();
        }
        if (t < NB) {
            int excl = sm[t] - v;
            bbase[t] = excl;
            bcur[t] = excl;
        }
        if (t == 0) offs[NN] = EE;
        return;
    }
    __shared__ int carry;
    __shared__ int tl[KK];
    if (t == 0) carry = 0;
    for (int i = t; i < MAXT; i += 256) tmap_b[i] = -1;
    __syncthreads();
    for (int c = 0; c < SCH; ++c) {
        int i = c * 256 + t;
        int v = (i < NBC) ? nbc[i] : 0;
        sm[t] = v;
        __syncthreads();
        for (int off = 1; off < 256; off <<= 1) {
            int y = (t >= off) ? sm[t - off] : 0;
            __syncthreads();
            sm[t] += y;
            __syncthreads();
        }
        int base = carry;
        int excl = base + sm[t] - v;
        if (i < NBC) {
            gbase[i] = excl;
            if ((i % NB) == 0) koff[i / NB] = excl;
        }
        __syncthreads();
        if (t == 255) carry = base + sm[255];
        __syncthreads();
    }
    if (t == 0) {
        koff[KK] = NN;
        int run = 0;
        for (int k = 0; k < KK; ++k) {
            tl[k] = run;
            int cnt = ((k == KK - 1) ? NN : koff[k + 1]) - koff[k];
            run += (cnt + 63) / 64;
        }
    }
    __syncthreads();
    if (t < KK) {
        int k = t;
        int kb = koff[k];
        int ke = (k == KK - 1) ? NN : koff[k + 1];
        int nt = (ke - kb + 63) / 64;
        for (int tt = 0; tt < nt; ++tt) {
            tmap_b[tl[k] + tt] = k;
            tmap_s[tl[k] + tt] = kb + tt * 64;
        }
    }
}

// ================ K4: coarse_scatter (BKE=2048, packed 4B edges) + nb_scatter ================
__global__ __launch_bounds__(256) void scatter_k(const int* __restrict__ src,
                                                 const int* __restrict__ dst,
                                                 int* __restrict__ bcur,
                                                 unsigned* __restrict__ ebuf,
                                                 const int* __restrict__ na,
                                                 const int* __restrict__ gbase,
                                                 int* __restrict__ perm) {
    __shared__ int s1[NB];
    __shared__ int s2[NB];
    const int t = threadIdx.x, b = blockIdx.x;
    if (b < GR1) {
        for (int i = t; i < NB; i += 256) s1[i] = 0;
        __syncthreads();
        const int base = b * BKE;
        unsigned mypk[8]; int mybin[8], myrank[8];
        #pragma unroll
        for (int u = 0; u < 8; ++u) {
            int e = base + t + u * 256;
            if (e < EE) {
                int d = dst[e];
                int s = src[e];
                mybin[u] = d >> 9;
                mypk[u] = (unsigned)s |
                          ((unsigned)(((d & 511) << 1) | (s < C0 ? 0 : 1)) << 17);
                myrank[u] = atomicAdd(&s1[mybin[u]], 1);
            } else mybin[u] = -1;
        }
        __syncthreads();
        for (int i = t; i < NB; i += 256) {
            int c = s1[i];
            s2[i] = c ? atomicAdd(&bcur[i], c) : 0;
        }
        __syncthreads();
        #pragma unroll
        for (int u = 0; u < 8; ++u) {
            if (mybin[u] >= 0) {
                ebuf[s2[mybin[u]] + myrank[u]] = mypk[u];
            }
        }
    } else {
        const int nb_ = b - GR1;
        if (t < KK) { s1[t] = 0; s2[t] = gbase[t * NB + nb_]; }
        __syncthreads();
        #pragma unroll
        for (int u = 0; u < 2; ++u) {
            int n = nb_ * 512 + t + u * 256;
            if (n < NN) {
                int k = na[n];
                int r = atomicAdd(&s1[k], 1);
                perm[s2[k] + r] = n;
            }
        }
    }
}

// ================ r2: per-bucket exact CSR (1024 threads/block) ================
__global__ __launch_bounds__(1024) void fine_scatter(const unsigned* __restrict__ ebuf,
                                                     const int* __restrict__ bbase,
                                                     const int* __restrict__ bend,
                                                     int* __restrict__ offs,
                                                     int* __restrict__ split,
                                                     int* __restrict__ ssrc) {
    __shared__ int hist[1024];
    __shared__ int lofs[1024];
    __shared__ int sm[1024];
    const int t = threadIdx.x, b = blockIdx.x;
    const int beg = bbase[b], end = bend[b];
    hist[t] = 0;
    __syncthreads();
    for (int j = beg + t; j < end; j += 1024) {
        atomicAdd(&hist[ebuf[j] >> 17], 1);
    }
    __syncthreads();
    int v = hist[t];
    sm[t] = v;
    __syncthreads();
    for (int off = 1; off < 1024; off <<= 1) {
        int y = (t >= off) ? sm[t - off] : 0;
        __syncthreads();
        sm[t] += y;
        __syncthreads();
    }
    lofs[t] = sm[t] - v;   // exclusive prefix
    __syncthreads();
    if (t < 512) {
        int n = b * 512 + t;
        if (n < NN) {
            offs[n]  = beg + lofs[2 * t];
            split[n] = beg + lofs[2 * t + 1];
        }
    }
    __syncthreads();
    for (int j = beg + t; j < end; j += 1024) {
        unsigned pk = ebuf[j];
        int pos = beg + atomicAdd(&lofs[pk >> 17], 1);
        ssrc[pos] = (int)(pk & 0x1FFFFu);
    }
}

// ================ spmm v3: 8 lanes/node (16B each), 32 nodes/block, 8-deep ILP ================
__global__ __launch_bounds__(256) void spmm(const ushortT* __restrict__ rows,
                                            const int* __restrict__ offs,
                                            const int* __restrict__ splt,
                                            const int* __restrict__ ssrc,
                                            ushortT* __restrict__ aggb) {
    const int t = threadIdx.x;
    const int g = t >> 3, c8 = t & 7;
    const int n = blockIdx.x * 32 + g;
    const int beg = offs[n], endf = offs[n + 1];
    const int ge = splt ? splt[n] : endf;
    float a[8] = {}, c[8] = {};
    int j = beg;
    for (; j + 8 <= ge; j += 8) {
        int s0 = ssrc[j + 0], s1 = ssrc[j + 1], s2 = ssrc[j + 2], s3 = ssrc[j + 3];
        int s4 = ssrc[j + 4], s5 = ssrc[j + 5], s6 = ssrc[j + 6], s7 = ssrc[j + 7];
        uint4 v0 = *(const uint4*)(rows + (size_t)s0 * HID + c8 * 8);
        uint4 v1 = *(const uint4*)(rows + (size_t)s1 * HID + c8 * 8);
        uint4 v2 = *(const uint4*)(rows + (size_t)s2 * HID + c8 * 8);
        uint4 v3 = *(const uint4*)(rows + (size_t)s3 * HID + c8 * 8);
        uint4 v4 = *(const uint4*)(rows + (size_t)s4 * HID + c8 * 8);
        uint4 v5 = *(const uint4*)(rows + (size_t)s5 * HID + c8 * 8);
        uint4 v6 = *(const uint4*)(rows + (size_t)s6 * HID + c8 * 8);
        uint4 v7 = *(const uint4*)(rows + (size_t)s7 * HID + c8 * 8);
        acc8f(a, v0); acc8f(c, v1); acc8f(a, v2); acc8f(c, v3);
        acc8f(a, v4); acc8f(c, v5); acc8f(a, v6); acc8f(c, v7);
    }
    if (j + 4 <= ge) {
        int s0 = ssrc[j + 0], s1 = ssrc[j + 1], s2 = ssrc[j + 2], s3 = ssrc[j + 3];
        uint4 v0 = *(const uint4*)(rows + (size_t)s0 * HID + c8 * 8);
        uint4 v1 = *(const uint4*)(rows + (size_t)s1 * HID + c8 * 8);
        uint4 v2 = *(const uint4*)(rows + (size_t)s2 * HID + c8 * 8);
        uint4 v3 = *(const uint4*)(rows + (size_t)s3 * HID + c8 * 8);
        acc8f(a, v0); acc8f(c, v1); acc8f(a, v2); acc8f(c, v3);
        j += 4;
    }
    for (; j < ge; ++j) {
        uint4 v = *(const uint4*)(rows + (size_t)ssrc[j] * HID + c8 * 8);
        acc8f(a, v);
    }
    const float inv = 1.0f / fmaxf((float)(endf - beg), 1.0f);
    #pragma unroll
    for (int i = 0; i < 8; ++i) a[i] = (a[i] + c[i]) * inv;
    uint4 o;
    o.x = pk2(a[0], a[1]); o.y = pk2(a[2], a[3]);
    o.z = pk2(a[4], a[5]); o.w = pk2(a[6], a[7]);
    *(uint4*)(aggb + (size_t)n * HID + c8 * 8) = o;
}

// ================ op GEMM via MFMA: k-bucketed tiles, bf16 agg -> htb ================
__global__ __launch_bounds__(256) void op_gemm(const ushortT* __restrict__ aggb,
                                               const ushortT* __restrict__ hb,
                                               const int* __restrict__ perm,
                                               const int* __restrict__ koff,
                                               const int* __restrict__ tmap_b,
                                               const int* __restrict__ tmap_s,
                                               const float* __restrict__ op_W,
                                               const float* __restrict__ op_b,
                                               const float* __restrict__ emb_W,
                                               const float* __restrict__ emb_b,
                                               ushortT* __restrict__ htb) {
    __shared__ ushortT Ak[64 * AP];
    __shared__ ushortT Bk[64 * AP];
    __shared__ int idx[64];
    const int bk = tmap_b[blockIdx.x];
    if (bk < 0) return;
    const int start = tmap_s[blockIdx.x];
    const int kend = koff[bk + 1];
    const int tid = threadIdx.x;
    const int rr = tid >> 2, q = tid & 3;
    if (tid < 64) {
        int p = start + tid;
        idx[tid] = (p < kend) ? perm[p] : -1;
    }
    __syncthreads();
    {
        int n = idx[rr];
        uint4 a0 = {0,0,0,0}, a1 = {0,0,0,0};
        if (n >= 0) {
            const uint4* p = (const uint4*)(aggb + (size_t)n * HID + q * 16);
            a0 = p[0]; a1 = p[1];
        }
        *(uint4*)&Ak[rr * AP + q * 16] = a0;
        *(uint4*)&Ak[rr * AP + q * 16 + 8] = a1;
    }
    {
        const float* wp = op_W + (size_t)bk * HID * HID;
        #pragma unroll
        for (int j = 0; j < 16; ++j) {
            Bk[rr * AP + q * 16 + j] = f2b(wp[(size_t)(q * 16 + j) * HID + rr]);
        }
    }
    __syncthreads();
    const int w = tid >> 6, l = tid & 63;
    const int lr = l & 15, g = l >> 4;
    f32x4 acc[4] = {{0.f,0.f,0.f,0.f},{0.f,0.f,0.f,0.f},{0.f,0.f,0.f,0.f},{0.f,0.f,0.f,0.f}};
    #pragma unroll
    for (int s = 0; s < 2; ++s) {
        bf16x8 af = *(const bf16x8*)&Ak[(w * 16 + lr) * AP + s * 32 + g * 8];
        #pragma unroll
        for (int n = 0; n < 4; ++n) {
            bf16x8 bf = *(const bf16x8*)&Bk[(n * 16 + lr) * AP + s * 32 + g * 8];
            acc[n] = __builtin_amdgcn_mfma_f32_16x16x32_bf16(af, bf, acc[n], 0, 0, 0);
        }
    }
    #pragma unroll
    for (int n = 0; n < 4; ++n) {
        const int col = n * 16 + lr;
        float ob = op_b[bk * HID + col];
        #pragma unroll
        for (int i = 0; i < 4; ++i) {
            int node = idx[w * 16 + g * 4 + i];
            if (node < 0) continue;
            float v = acc[n][i] + ob;
            if (node < C0) {
                v += b2f(hb[(size_t)node * HID + col]);
            } else {
                int si = (node < C0 + C1) ? 0 : 1;
                int rn = node - C0 - si * C1;
                v += emb_W[((size_t)si * C1 + rn) * HID + col] + emb_b[si * HID + col];
            }
            htb[(size_t)node * HID + col] = f2b(v);
        }
    }
}

// ================ fc GEMM via MFMA: contiguous segment rows, in-place htb ================
__global__ __launch_bounds__(256) void fc_gemm(ushortT* __restrict__ htb,
                                               const float* __restrict__ fc_W,
                                               const float* __restrict__ fc_b) {
    __shared__ ushortT Ak[64 * AP];
    __shared__ ushortT Bk[64 * AP];
    const int si = (blockIdx.x < FCT) ? 0 : 1;
    const int t0 = blockIdx.x - si * FCT;
    const int row0 = C0 + si * C1 + t0 * 64;
    const int lim = C0 + (si + 1) * C1;
    const int tid = threadIdx.x;
    const int rr = tid >> 2, q = tid & 3;
    {
        int n = row0 + rr;
        uint4 a0 = {0,0,0,0}, a1 = {0,0,0,0};
        if (n < lim) {
            const uint4* p = (const uint4*)(htb + (size_t)n * HID + q * 16);
            a0 = p[0]; a1 = p[1];
        }
        *(uint4*)&Ak[rr * AP + q * 16] = a0;
        *(uint4*)&Ak[rr * AP + q * 16 + 8] = a1;
    }
    {
        const float* wp = fc_W + (size_t)si * HID * HID;
        #pragma unroll
        for (int j = 0; j < 16; ++j) {
            Bk[rr * AP + q * 16 + j] = f2b(wp[(size_t)(q * 16 + j) * HID + rr]);
        }
    }
    __syncthreads();
    const int w = tid >> 6, l = tid & 63;
    const int lr = l & 15, g = l >> 4;
    f32x4 acc[4] = {{0.f,0.f,0.f,0.f},{0.f,0.f,0.f,0.f},{0.f,0.f,0.f,0.f},{0.f,0.f,0.f,0.f}};
    #pragma unroll
    for (int s = 0; s < 2; ++s) {
        bf16x8 af = *(const bf16x8*)&Ak[(w * 16 + lr) * AP + s * 32 + g * 8];
        #pragma unroll
        for (int n = 0; n < 4; ++n) {
            bf16x8 bf = *(const bf16x8*)&Bk[(n * 16 + lr) * AP + s * 32 + g * 8];
            acc[n] = __builtin_amdgcn_mfma_f32_16x16x32_bf16(af, bf, acc[n], 0, 0, 0);
        }
    }
    #pragma unroll
    for (int n = 0; n < 4; ++n) {
        const int col = n * 16 + lr;
        float fb = fc_b[si * HID + col];
        #pragma unroll
        for (int i = 0; i < 4; ++i) {
            int node = row0 + w * 16 + g * 4 + i;
            if (node >= lim) continue;
            htb[(size_t)node * HID + col] = f2b(acc[n][i] + fb);
        }
    }
}

// ================ gnn GEMM via MFMA + elu + logits (reads bf16 agg) ================
__global__ __launch_bounds__(256) void gnn_logits(const ushortT* __restrict__ aggb,
                                                  const float* __restrict__ gnn_W,
                                                  const float* __restrict__ gnn_b,
                                                  const float* __restrict__ out_W,
                                                  const float* __restrict__ out_b,
                                                  float* __restrict__ out) {
    __shared__ ushortT Ak[64 * AP];
    __shared__ ushortT Bk[64 * AP];
    __shared__ float Em[64][65];
    __shared__ float Wo[64 * NCLS];
    const int row0 = blockIdx.x * 64;
    const int tid = threadIdx.x;
    const int rr = tid >> 2, q = tid & 3;
    {
        int n = row0 + rr;
        uint4 a0 = {0,0,0,0}, a1 = {0,0,0,0};
        if (n < NN) {
            const uint4* p = (const uint4*)(aggb + (size_t)n * HID + q * 16);
            a0 = p[0]; a1 = p[1];
        }
        *(uint4*)&Ak[rr * AP + q * 16] = a0;
        *(uint4*)&Ak[rr * AP + q * 16 + 8] = a1;
    }
    {
        #pragma unroll
        for (int j = 0; j < 16; ++j) {
            Bk[rr * AP + q * 16 + j] = f2b(gnn_W[(size_t)(q * 16 + j) * HID + rr]);
        }
    }
    *(float4*)(&Wo[tid * 4]) = *(const float4*)(out_W + tid * 4);
    __syncthreads();
    const int w = tid >> 6, l = tid & 63;
    const int lr = l & 15, g = l >> 4;
    f32x4 acc[4] = {{0.f,0.f,0.f,0.f},{0.f,0.f,0.f,0.f},{0.f,0.f,0.f,0.f},{0.f,0.f,0.f,0.f}};
    #pragma unroll
    for (int s = 0; s < 2; ++s) {
        bf16x8 af = *(const bf16x8*)&Ak[(w * 16 + lr) * AP + s * 32 + g * 8];
        #pragma unroll
        for (int n = 0; n < 4; ++n) {
            bf16x8 bf = *(const bf16x8*)&Bk[(n * 16 + lr) * AP + s * 32 + g * 8];
            acc[n] = __builtin_amdgcn_mfma_f32_16x16x32_bf16(af, bf, acc[n], 0, 0, 0);
        }
    }
    #pragma unroll
    for (int n = 0; n < 4; ++n) {
        const int col = n * 16 + lr;
        float gb = gnn_b[col];
        #pragma unroll
        for (int i = 0; i < 4; ++i) {
            int lrow = w * 16 + g * 4 + i;
            int node = row0 + lrow;
            float v = acc[n][i] + gb;
            v = (v > 0.f) ? v : expm1f(v);
            Em[lrow][col] = v;
            if (node < NN) out[(size_t)node * HID + col] = v;
        }
    }
    __syncthreads();
    const int r = tid >> 2, cq = (tid & 3) * 4;
    float l0 = 0.f, l1 = 0.f, l2 = 0.f, l3 = 0.f;
    #pragma unroll 8
    for (int j = 0; j < 64; ++j) {
        float e = Em[r][j];
        float4 wv = *(const float4*)(&Wo[j * NCLS + cq]);
        l0 += e * wv.x; l1 += e * wv.y; l2 += e * wv.z; l3 += e * wv.w;
    }
    int n = row0 + r;
    if (n < NN) {
        float4 ob = *(const float4*)(out_b + cq);
        float4 lg;
        lg.x = l0 + ob.x; lg.y = l1 + ob.y; lg.z = l2 + ob.z; lg.w = l3 + ob.w;
        const size_t lbase = (size_t)NN * HID;
        *(float4*)(out + lbase + (size_t)n * NCLS + cq) = lg;
        *(float4*)(out + lbase + (size_t)NN * NCLS + (size_t)n * NCLS + cq) = lg;
    }
}

extern "C" void kernel_launch(void* const* d_in, const int* in_sizes, int n_in,
                              void* d_out, int out_size, void* d_ws, size_t ws_size,
                              hipStream_t stream) {
    const float* feats0 = (const float*)d_in[0];
    const float* W_pre  = (const float*)d_in[1];
    const float* b_pre  = (const float*)d_in[2];
    const float* emb_W  = (const float*)d_in[3];
    const float* emb_b  = (const float*)d_in[4];
    const float* op_W   = (const float*)d_in[5];
    const float* op_b   = (const float*)d_in[6];
    const float* fc_W   = (const float*)d_in[7];
    const float* fc_b   = (const float*)d_in[8];
    const float* gnn_W  = (const float*)d_in[9];
    const float* gnn_b  = (const float*)d_in[10];
    const float* out_W  = (const float*)d_in[11];
    const float* out_b  = (const float*)d_in[12];
    const int* src         = (const int*)d_in[13];
    const int* dst         = (const int*)d_in[14];
    const int* node_assign = (const int*)d_in[15];
    float* out = (float*)d_out;

    // workspace layout (~38 MB). aggb (12.8MB) aliases ebuf (6.4MB packed).
    ushortT* hb  = (ushortT*)d_ws;                     // C0*HID bf16
    ushortT* htb = hb + (size_t)C0 * HID;              // NN*HID bf16
    ushortT* aggb = htb + (size_t)NN * HID;            // NN*HID bf16 (union w/ ebuf)
    unsigned* ebuf = (unsigned*)aggb;                  // EE u32 (alias)
    ushortT* WT = aggb + (size_t)NN * HID;             // 64*512 bf16
    int* ssrc   = (int*)(WT + (size_t)HID * DIN);      // EE
    int* offs   = ssrc + EE;                           // NN+1
    int* split  = offs + NN + 1;                       // NN
    int* perm   = split + NN;                          // NN
    int* nbc    = perm + NN;                           // NBC
    int* gbase  = nbc + NBC;                           // NBC
    int* koff   = gbase + NBC;                         // KK+1
    int* tmap_b = koff + KK + 1;                       // MAXT
    int* tmap_s = tmap_b + MAXT;                       // MAXT
    int* bcnt   = tmap_s + MAXT;                       // NB
    int* bbase  = bcnt + NB;                           // NB
    int* bcur   = bbase + NB;                          // NB

    zero_wt<<<17, 256, 0, stream>>>(W_pre, WT, bcnt);
    fused_a<<<PMB + GR1 + NB, 256, 0, stream>>>(feats0, WT, b_pre, dst, node_assign,
                                                bcnt, nbc, hb);
    scan_k<<<2, 256, 0, stream>>>(bcnt, bbase, bcur, offs, nbc, gbase, koff, tmap_b, tmap_s);
    scatter_k<<<GR1 + NB, 256, 0, stream>>>(src, dst, bcur, ebuf, node_assign, gbase, perm);
    fine_scatter<<<NB, 1024, 0, stream>>>(ebuf, bbase, bcur, offs, split, ssrc);
    spmm<<<NN / 32, 256, 0, stream>>>(hb, offs, split, ssrc, aggb);          // filtered
    op_gemm<<<MAXT, 256, 0, stream>>>(aggb, hb, perm, koff, tmap_b, tmap_s,
                                      op_W, op_b, emb_W, emb_b, htb);
    fc_gemm<<<2 * FCT, 256, 0, stream>>>(htb, fc_W, fc_b);
    spmm<<<NN / 32, 256, 0, stream>>>(htb, offs, nullptr, ssrc, aggb);       // full
    gnn_logits<<<GNT, 256, 0, stream>>>(aggb, gnn_W, gnn_b, out_W, out_b, out);
}